// Round 10
// baseline (759.890 us; speedup 1.0000x reference)
//
#include <hip/hip_runtime.h>

#define Bsz  2048
#define Tlen 512
#define Din  32
#define Hd   64
#define BT   16            // batches per block (MFMA N=16)
#define HS   72            // h row stride in f16 elems (144B, 16B-aligned)
#define SLOT (BT * HS)     // one h snapshot = 1152 f16 = 2304 B
#define RS   8             // h1 ring slots (producer may lead consumer by <= 8)
#define SPINB 4096         // bounded spin: bug -> fast wrong answer, never a hang

typedef _Float16 half8 __attribute__((ext_vector_type(8)));
typedef _Float16 half4 __attribute__((ext_vector_type(4)));
typedef float    f32x4 __attribute__((ext_vector_type(4)));

#define MFMA(a, b, c) __builtin_amdgcn_mfma_f32_16x16x32_f16((a), (b), (c), 0, 0, 0)

__device__ __forceinline__ half8 load8s(const float* p, float s) {
    half8 r;
#pragma unroll
    for (int j = 0; j < 8; ++j) r[j] = (_Float16)(p[j] * s);
    return r;
}
__device__ __forceinline__ half8 cvt8(float4 a, float4 b) {
    half8 r;
    r[0] = (_Float16)a.x; r[1] = (_Float16)a.y; r[2] = (_Float16)a.z; r[3] = (_Float16)a.w;
    r[4] = (_Float16)b.x; r[5] = (_Float16)b.y; r[6] = (_Float16)b.z; r[7] = (_Float16)b.w;
    return r;
}

// weights pre-scaled by -log2(e) (r,z) and -2*log2(e) (n). With E = 2^(scaled):
//   sigma(raw) = 1/(1+E),  tanh(raw_n) = (1-E_n)/(1+E_n)
// GRU update folds to ONE rcp:  h' = [E_z(1-E_n) + h(1+E_n)] / [(1+E_z)(1+E_n)]
__device__ __forceinline__ half4 gate4(const f32x4& gr, const f32x4& gz,
                                       const f32x4& anx, const f32x4& anh,
                                       float* hst) {
    half4 pk;
#pragma unroll
    for (int r = 0; r < 4; ++r) {
        float Er = __builtin_amdgcn_exp2f(gr[r]);
        float rr = __builtin_amdgcn_rcpf(1.0f + Er);
        float yy = anx[r] + rr * anh[r];
        float En = __builtin_amdgcn_exp2f(yy);
        float Ez = __builtin_amdgcn_exp2f(gz[r]);
        float num = Ez * (1.0f - En) + hst[r] * (1.0f + En);
        float den = (1.0f + Ez) * (1.0f + En);
        hst[r] = num * __builtin_amdgcn_rcpf(den);
        pk[r] = (_Float16)hst[r];
    }
    return pk;
}

// spin until LDS counter CTR >= TGT, per-wave cached in CACHE. Steady state:
// cache satisfies -> zero cost. sched_barrier fences later LDS reads from
// hoisting above the gate (rule #18).
#define SPIN_GE(CTR, TGT, CACHE)                                         \
  do {                                                                   \
    if ((CACHE) < (TGT)) {                                               \
      int v_ = (CACHE);                                                  \
      for (int sp_ = 0; v_ < (TGT) && sp_ < SPINB; ++sp_) {              \
        if (lane == 0)                                                   \
          v_ = __hip_atomic_load(&CTR, __ATOMIC_ACQUIRE,                 \
                                 __HIP_MEMORY_SCOPE_WORKGROUP);          \
        v_ = __builtin_amdgcn_readfirstlane(v_);                         \
        if (v_ < (TGT)) __builtin_amdgcn_s_sleep(1);                     \
      }                                                                  \
      (CACHE) = v_;                                                      \
    }                                                                    \
    __builtin_amdgcn_sched_barrier(0);                                   \
  } while (0)

// ===========================================================================
// Wave-specialized GRU: 128 blocks x 128 threads (2 waves).
//   wave 0 (L1): computes the ENTIRE layer-1 step for its 16-batch tile.
//     M = 192 gate rows = 12 MFMA tiles, all in one wave (weights ~144 VGPR,
//     __launch_bounds__(128,1) -> 512-VGPR budget). h1[t-1]->h1[t] is
//     SAME-WAVE through an LDS ring slot: lgkmcnt ordering only, NO barrier,
//     NO flags on the recurrence chain. h1[t] ring slot doubles as the
//     handoff to L2. After write: lgkmcnt(0) + lane0 c1++ (release).
//   wave 1 (L2): polls c1 (cached: producer leads by up to RS, so reloads
//     amortize to ~1/lead steps), reads h1[t] + own h2[t-1] (same-wave,
//     2-slot ring), 48 MFMAs, gates, acks u1++ after reads complete.
//     Final step's h2 stays in registers -> FC head via shfl-reduce.
// L1 throttles on u1 >= t-(RS-1) before overwriting a slot (bounded buffer;
// off the system critical path since L2 is the long pole). Deadlock-free:
// L1@t needs L2>=t-7, L2@t needs L1>=t+1 -- no cycle. Spins bounded.
// Arithmetic bit-identical to the 297us mono kernel (same accumulator split,
// same MFMA K-order, same f16 rounding points, h-state f32 in registers).
// ===========================================================================
__global__ __launch_bounds__(128, 1)
void gru_ws(const float* __restrict__ x,
            const float* __restrict__ Wih0, const float* __restrict__ Whh0,
            const float* __restrict__ bih0, const float* __restrict__ bhh0,
            const float* __restrict__ Wih1, const float* __restrict__ Whh1,
            const float* __restrict__ bih1, const float* __restrict__ bhh1,
            const float* __restrict__ fcw,  const float* __restrict__ fcb,
            float* __restrict__ out)
{
    __shared__ _Float16 ring[RS * SLOT];   // h1 ring (18432 B)
    __shared__ _Float16 h2r[2 * SLOT];     // h2 self-ring (4608 B)
    __shared__ int c1, u1;

    const int tid  = threadIdx.x;
    const int lane = tid & 63;
    const int wv   = tid >> 6;             // 0 = L1 wave, 1 = L2 wave
    const int q    = lane >> 4;            // k-chunk (B-frag) / row-group (C)
    const int m    = lane & 15;            // batch (B col) AND W row within tile
    const int b0   = blockIdx.x << 4;

    // zero h1[-1] slot (RS-1) and h2[-1] slot (1); counters
    for (int idx = tid; idx < SLOT; idx += 128) {
        ring[(RS - 1) * SLOT + idx] = (_Float16)0.f;
        h2r[SLOT + idx]             = (_Float16)0.f;
    }
    if (tid == 0) { c1 = 0; u1 = 0; }

    const float sRZ = -1.44269504f;        // -log2(e)
    const float sN  = -2.88539008f;        // -2*log2(e)
    const int rd = m * HS + q * 8;         // B-frag read: batch m, k = q*8.. (+32 for kf1)
    const int wr = m * HS + q * 4;         // C write: batch m, col 16g+4q (+16g)
    float hst[16];
#pragma unroll
    for (int i = 0; i < 16; ++i) hst[i] = 0.f;

    __syncthreads();                       // init visible; only barrier in kernel

    if (wv == 0) {
        // ================= L1 wave: all 12 M-tiles of layer 1 =================
        half8 wxr[4], wxz[4], wxn[4];          // W_ih0: 12 tiles, K=32 (1 frag)
        half8 whr[4][2], whz[4][2], whn[4][2]; // W_hh0: 12 tiles x 2 K-frags
        f32x4 br[4], bz[4], bnx[4], bnh[4];
#pragma unroll
        for (int g = 0; g < 4; ++g) {
            wxr[g] = load8s(Wih0 + (      16 * g + m) * Din + q * 8, sRZ);
            wxz[g] = load8s(Wih0 + ( 64 + 16 * g + m) * Din + q * 8, sRZ);
            wxn[g] = load8s(Wih0 + (128 + 16 * g + m) * Din + q * 8, sN);
#pragma unroll
            for (int kf = 0; kf < 2; ++kf) {
                whr[g][kf] = load8s(Whh0 + (      16*g + m) * Hd + kf*32 + q*8, sRZ);
                whz[g][kf] = load8s(Whh0 + ( 64 + 16*g + m) * Hd + kf*32 + q*8, sRZ);
                whn[g][kf] = load8s(Whh0 + (128 + 16*g + m) * Hd + kf*32 + q*8, sN);
            }
#pragma unroll
            for (int u = 0; u < 4; ++u) {
                const int c = 16 * g + 4 * q + u;
                br[g][u]  = sRZ * (bih0[c] + bhh0[c]);
                bz[g][u]  = sRZ * (bih0[64 + c] + bhh0[64 + c]);
                bnx[g][u] = sN * bih0[128 + c];
                bnh[g][u] = sN * bhh0[128 + c];
            }
        }
        // x: lane (q,m) reads x[b0+m][t][8q..8q+7]; 2-step parity prefetch
        const float* xgp = x + (size_t)(b0 + m) * (Tlen * Din) + q * 8;
        float4 x0a = *(const float4*)(xgp),       x0b = *(const float4*)(xgp + 4);
        float4 x1a = *(const float4*)(xgp + Din), x1b = *(const float4*)(xgp + Din + 4);
        int u1v = 0;

        auto l1step = [&](int T, float4& XA, float4& XB) {
            if (T >= RS) SPIN_GE(u1, T - (RS - 1), u1v);   // ring-full guard
            half8 ax = cvt8(XA, XB);
            { const int nx = (T + 2 < Tlen) ? T + 2 : Tlen - 1;
              const float* p = xgp + (size_t)nx * Din;
              XA = *(const float4*)p; XB = *(const float4*)(p + 4); }
            const _Float16* s1 = ring + ((T + RS - 1) & (RS - 1)) * SLOT + rd;
            half8 bh0 = *(const half8*)s1;            // h1[T-1] k 0..31
            half8 bh1 = *(const half8*)(s1 + 32);     // h1[T-1] k 32..63
            f32x4 gr4[4], gz4[4], gnx[4], gnh[4];
#pragma unroll
            for (int g = 0; g < 4; ++g) {
                f32x4 arx = MFMA(wxr[g], ax, br[g]);
                f32x4 arh = {0.f, 0.f, 0.f, 0.f};
                arh = MFMA(whr[g][0], bh0, arh); arh = MFMA(whr[g][1], bh1, arh);
                f32x4 azx = MFMA(wxz[g], ax, bz[g]);
                f32x4 azh = {0.f, 0.f, 0.f, 0.f};
                azh = MFMA(whz[g][0], bh0, azh); azh = MFMA(whz[g][1], bh1, azh);
                gnx[g] = MFMA(wxn[g], ax, bnx[g]);
                f32x4 anh = bnh[g];
                anh = MFMA(whn[g][0], bh0, anh); anh = MFMA(whn[g][1], bh1, anh);
                gnh[g] = anh;
                gr4[g] = arx + arh; gz4[g] = azx + azh;
            }
            _Float16* wp = ring + (T & (RS - 1)) * SLOT + wr;
#pragma unroll
            for (int g = 0; g < 4; ++g) {
                half4 pk = gate4(gr4[g], gz4[g], gnx[g], gnh[g], &hst[4 * g]);
                *(half4*)(wp + 16 * g) = pk;          // col 16g+4q, batch m
            }
            asm volatile("s_waitcnt lgkmcnt(0)" ::: "memory");  // writes retired
            if (lane == 0)
                __hip_atomic_fetch_add(&c1, 1, __ATOMIC_RELEASE,
                                       __HIP_MEMORY_SCOPE_WORKGROUP);
        };
        for (int t = 0; t < Tlen; t += 2) {
            l1step(t,     x0a, x0b);
            l1step(t + 1, x1a, x1b);
        }
    } else {
        // ================= L2 wave: all 12 M-tiles of layer 2 + FC =================
        half8 wir[4][2], wiz[4][2], win[4][2]; // W_ih1: 12 tiles x 2 K-frags
        half8 whr[4][2], whz[4][2], whn[4][2]; // W_hh1: 12 tiles x 2 K-frags
        f32x4 br[4], bz[4], bnx[4], bnh[4];
        float fcv[16];
#pragma unroll
        for (int g = 0; g < 4; ++g) {
#pragma unroll
            for (int kf = 0; kf < 2; ++kf) {
                wir[g][kf] = load8s(Wih1 + (      16*g + m) * Hd + kf*32 + q*8, sRZ);
                wiz[g][kf] = load8s(Wih1 + ( 64 + 16*g + m) * Hd + kf*32 + q*8, sRZ);
                win[g][kf] = load8s(Wih1 + (128 + 16*g + m) * Hd + kf*32 + q*8, sN);
                whr[g][kf] = load8s(Whh1 + (      16*g + m) * Hd + kf*32 + q*8, sRZ);
                whz[g][kf] = load8s(Whh1 + ( 64 + 16*g + m) * Hd + kf*32 + q*8, sRZ);
                whn[g][kf] = load8s(Whh1 + (128 + 16*g + m) * Hd + kf*32 + q*8, sN);
            }
#pragma unroll
            for (int u = 0; u < 4; ++u) {
                const int c = 16 * g + 4 * q + u;
                br[g][u]  = sRZ * (bih1[c] + bhh1[c]);
                bz[g][u]  = sRZ * (bih1[64 + c] + bhh1[64 + c]);
                bnx[g][u] = sN * bih1[128 + c];
                bnh[g][u] = sN * bhh1[128 + c];
                fcv[4 * g + u] = fcw[c];
            }
        }
        int c1v = 0;

        auto l2step = [&](int T) {
            SPIN_GE(c1, T + 1, c1v);                  // h1[T] ready (cached)
            const _Float16* s1 = ring + (T & (RS - 1)) * SLOT + rd;
            half8 bx0 = *(const half8*)s1;            // h1[T]
            half8 bx1 = *(const half8*)(s1 + 32);
            const _Float16* s2 = h2r + ((T + 1) & 1) * SLOT + rd;
            half8 bh0 = *(const half8*)s2;            // h2[T-1] (same-wave)
            half8 bh1 = *(const half8*)(s2 + 32);
            asm volatile("s_waitcnt lgkmcnt(0)" ::: "memory");  // reads landed
            __builtin_amdgcn_sched_barrier(0);
            if (lane == 0)                            // release ring slot early
                __hip_atomic_fetch_add(&u1, 1, __ATOMIC_RELEASE,
                                       __HIP_MEMORY_SCOPE_WORKGROUP);
            f32x4 gr4[4], gz4[4], gnx[4], gnh[4];
#pragma unroll
            for (int g = 0; g < 4; ++g) {
                f32x4 arx = MFMA(wir[g][0], bx0, br[g]);
                arx = MFMA(wir[g][1], bx1, arx);
                f32x4 arh = {0.f, 0.f, 0.f, 0.f};
                arh = MFMA(whr[g][0], bh0, arh); arh = MFMA(whr[g][1], bh1, arh);
                f32x4 azx = MFMA(wiz[g][0], bx0, bz[g]);
                azx = MFMA(wiz[g][1], bx1, azx);
                f32x4 azh = {0.f, 0.f, 0.f, 0.f};
                azh = MFMA(whz[g][0], bh0, azh); azh = MFMA(whz[g][1], bh1, azh);
                f32x4 anx = MFMA(win[g][0], bx0, bnx[g]);
                anx = MFMA(win[g][1], bx1, anx);
                gnx[g] = anx;
                f32x4 anh = bnh[g];
                anh = MFMA(whn[g][0], bh0, anh); anh = MFMA(whn[g][1], bh1, anh);
                gnh[g] = anh;
                gr4[g] = arx + arh; gz4[g] = azx + azh;
            }
            _Float16* wp = h2r + (T & 1) * SLOT + wr;
#pragma unroll
            for (int g = 0; g < 4; ++g) {
                half4 pk = gate4(gr4[g], gz4[g], gnx[g], gnh[g], &hst[4 * g]);
                *(half4*)(wp + 16 * g) = pk;
            }
        };
        for (int t = 0; t < Tlen; ++t) l2step(t);

        // FC head: hst holds h2[511][batch m][cols 16g+4q+u]; reduce over q
        float acc = 0.f;
#pragma unroll
        for (int i = 0; i < 16; ++i) acc += hst[i] * fcv[i];
        acc += __shfl_xor(acc, 16);
        acc += __shfl_xor(acc, 32);
        if (lane < 16) out[b0 + m] = acc + fcb[0];
    }
}

extern "C" void kernel_launch(void* const* d_in, const int* in_sizes, int n_in,
                              void* d_out, int out_size, void* d_ws, size_t ws_size,
                              hipStream_t stream) {
    gru_ws<<<dim3(Bsz / BT), dim3(128), 0, stream>>>(
        (const float*)d_in[0],
        (const float*)d_in[1], (const float*)d_in[2],
        (const float*)d_in[3], (const float*)d_in[4],
        (const float*)d_in[5], (const float*)d_in[6],
        (const float*)d_in[7], (const float*)d_in[8],
        (const float*)d_in[9], (const float*)d_in[10],
        (float*)d_out);
}